// Round 3
// baseline (133.860 us; speedup 1.0000x reference)
//
#include <hip/hip_runtime.h>
#include <cstddef>

#define B_SZ 32768
#define H_SZ 1024
#define N_SZ 4
#define C_SZ 1000
#define ROW_BLOCKS 512
#define ROWS_PER_BLOCK 64    // B_SZ / ROW_BLOCKS

typedef float f32x4 __attribute__((ext_vector_type(4)));

// ---- workspace layout (in floats) ----
#define PART_SUM   0                                  // 512*1024
#define PART_SQ    (PART_SUM + ROW_BLOCKS*H_SZ)       // 512*1024
#define WSUM_PART  (PART_SQ  + ROW_BLOCKS*H_SZ)       // 512
#define A_OFF      (WSUM_PART + ROW_BLOCKS)           // 1024  (gamma * inv_std)
#define C_OFF      (A_OFF + H_SZ)                     // 1024  (beta - mean * a)
#define SCAL_OFF   (C_OFF + H_SZ)                     // 1 (inv_wsum)  (+7 pad)
#define PCN_OFF    (SCAL_OFF + 8)                     // 4000 (p_cn, zeroed per launch)

// ---- output layout (floats) ----
#define OUT_IG  ((size_t)B_SZ * H_SZ)                 // 33554432
#define OUT_R   (OUT_IG + 1)                          // 33554433

// Pass 1: weighted column sums. Reads ALL rows (mask applied as a multiply) so
// the full 128 MiB of h_net lands in L3 for pass 3; total HBM read across the
// two passes is identical to the skip version, but pass-3 becomes all-L3.
__global__ void __launch_bounds__(256) k_colsum(const float* __restrict__ h,
                                                const int* __restrict__ mask,
                                                float* __restrict__ ws) {
    const int rb   = blockIdx.x;
    const int t    = threadIdx.x;          // 0..255
    const int row0 = rb * ROWS_PER_BLOCK;
    const int col  = t * 4;

    float4 sA = make_float4(0.f, 0.f, 0.f, 0.f);
    float4 qA = make_float4(0.f, 0.f, 0.f, 0.f);
    float4 sB = make_float4(0.f, 0.f, 0.f, 0.f);
    float4 qB = make_float4(0.f, 0.f, 0.f, 0.f);
    int mc = 0;

    const float* p = h + (size_t)row0 * H_SZ + col;
    for (int r = 0; r < ROWS_PER_BLOCK; r += 2) {
        const int   ma = mask[row0 + r];
        const int   mb = mask[row0 + r + 1];
        const float wa = (float)ma;
        const float wb = (float)mb;
        const float4 xa = *(const float4*)(p);
        const float4 xb = *(const float4*)(p + H_SZ);
        mc += ma + mb;

        float tx;
        tx = wa * xa.x; sA.x += tx; qA.x = fmaf(tx, xa.x, qA.x);
        tx = wa * xa.y; sA.y += tx; qA.y = fmaf(tx, xa.y, qA.y);
        tx = wa * xa.z; sA.z += tx; qA.z = fmaf(tx, xa.z, qA.z);
        tx = wa * xa.w; sA.w += tx; qA.w = fmaf(tx, xa.w, qA.w);

        tx = wb * xb.x; sB.x += tx; qB.x = fmaf(tx, xb.x, qB.x);
        tx = wb * xb.y; sB.y += tx; qB.y = fmaf(tx, xb.y, qB.y);
        tx = wb * xb.z; sB.z += tx; qB.z = fmaf(tx, xb.z, qB.z);
        tx = wb * xb.w; sB.w += tx; qB.w = fmaf(tx, xb.w, qB.w);

        p += 2 * H_SZ;
    }
    sA.x += sB.x; sA.y += sB.y; sA.z += sB.z; sA.w += sB.w;
    qA.x += qB.x; qA.y += qB.y; qA.z += qB.z; qA.w += qB.w;

    *(float4*)(ws + PART_SUM + (size_t)rb * H_SZ + col) = sA;
    *(float4*)(ws + PART_SQ  + (size_t)rb * H_SZ + col) = qA;
    if (t == 0) ws[WSUM_PART + rb] = (float)mc;
}

// Pass 2: finalize mean/var -> a[h], c[h], inv_wsum
__global__ void __launch_bounds__(256) k_colfinal(const float* __restrict__ gamma,
                                                  const float* __restrict__ beta,
                                                  float* __restrict__ ws) {
    __shared__ float red[256];
    const int t = threadIdx.x;

    // every block redundantly reduces the 512 wsum partials
    red[t] = ws[WSUM_PART + t] + ws[WSUM_PART + 256 + t];
    __syncthreads();
    for (int sft = 128; sft > 0; sft >>= 1) {
        if (t < sft) red[t] += red[t + sft];
        __syncthreads();
    }
    const float wsum = red[0];

    const int h = blockIdx.x * 256 + t;
    float s = 0.f, q = 0.f;
    for (int rb = 0; rb < ROW_BLOCKS; ++rb) {
        s += ws[PART_SUM + (size_t)rb * H_SZ + h];
        q += ws[PART_SQ  + (size_t)rb * H_SZ + h];
    }
    const float inv_w = 1.0f / wsum;
    const float mean  = s * inv_w;
    float var = q * inv_w - mean * mean;
    if (var < 0.f) var = 0.f;
    const float istd = rsqrtf(var + 1e-5f);
    const float a = gamma[h] * istd;
    const float c = beta[h] - mean * a;
    ws[A_OFF + h] = a;
    ws[C_OFF + h] = c;
    if (h == 0) ws[SCAL_OFF] = inv_w;
}

// Pass 3: fused normalize + (BxH)@(Hx4) + softmax + argmax routing + p_cn atomics
// one wave (64 lanes) per row; block = 4 waves. h_normed / routing stores are
// non-temporal so the 128 MiB write stream doesn't evict h_net from L3.
__global__ void __launch_bounds__(256) k_fused(const float* __restrict__ hin,
                                               const int* __restrict__ mask,
                                               const int* __restrict__ labels,
                                               const float* __restrict__ W,
                                               const float* __restrict__ bias,
                                               const float* __restrict__ ws,
                                               float* __restrict__ out,
                                               float* __restrict__ pcn) {
    const int wid  = threadIdx.x >> 6;
    const int lane = threadIdx.x & 63;
    const int row  = blockIdx.x * 4 + wid;

    const float* xr   = hin + (size_t)row * H_SZ;
    float*       outr = out + (size_t)row * H_SZ;

    float acc0 = 0.f, acc1 = 0.f, acc2 = 0.f, acc3 = 0.f;

#pragma unroll
    for (int ch = 0; ch < 4; ++ch) {
        const int h = ch * 256 + lane * 4;
        const float4 x = *(const float4*)(xr + h);
        const float4 a = *(const float4*)(ws + A_OFF + h);
        const float4 c = *(const float4*)(ws + C_OFF + h);
        float4 hn;
        hn.x = fmaf(x.x, a.x, c.x);
        hn.y = fmaf(x.y, a.y, c.y);
        hn.z = fmaf(x.z, a.z, c.z);
        hn.w = fmaf(x.w, a.w, c.w);
        f32x4 hv; hv.x = hn.x; hv.y = hn.y; hv.z = hn.z; hv.w = hn.w;
        __builtin_nontemporal_store(hv, (f32x4*)(outr + h));

        const float4 w0 = *(const float4*)(W + (size_t)(h + 0) * 4);
        const float4 w1 = *(const float4*)(W + (size_t)(h + 1) * 4);
        const float4 w2 = *(const float4*)(W + (size_t)(h + 2) * 4);
        const float4 w3 = *(const float4*)(W + (size_t)(h + 3) * 4);
        acc0 = fmaf(hn.x, w0.x, acc0); acc1 = fmaf(hn.x, w0.y, acc1);
        acc2 = fmaf(hn.x, w0.z, acc2); acc3 = fmaf(hn.x, w0.w, acc3);
        acc0 = fmaf(hn.y, w1.x, acc0); acc1 = fmaf(hn.y, w1.y, acc1);
        acc2 = fmaf(hn.y, w1.z, acc2); acc3 = fmaf(hn.y, w1.w, acc3);
        acc0 = fmaf(hn.z, w2.x, acc0); acc1 = fmaf(hn.z, w2.y, acc1);
        acc2 = fmaf(hn.z, w2.z, acc2); acc3 = fmaf(hn.z, w2.w, acc3);
        acc0 = fmaf(hn.w, w3.x, acc0); acc1 = fmaf(hn.w, w3.y, acc1);
        acc2 = fmaf(hn.w, w3.z, acc2); acc3 = fmaf(hn.w, w3.w, acc3);
    }

    // wave reduce-all (64 lanes)
#pragma unroll
    for (int off = 1; off < 64; off <<= 1) {
        acc0 += __shfl_xor(acc0, off);
        acc1 += __shfl_xor(acc1, off);
        acc2 += __shfl_xor(acc2, off);
        acc3 += __shfl_xor(acc3, off);
    }
    acc0 += bias[0]; acc1 += bias[1]; acc2 += bias[2]; acc3 += bias[3];

    // first-occurrence argmax (matches jnp.argmax)
    int amax = 0; float best = acc0;
    if (acc1 > best) { best = acc1; amax = 1; }
    if (acc2 > best) { best = acc2; amax = 2; }
    if (acc3 > best) { best = acc3; amax = 3; }

    // softmax (TEMPERATURE = 1)
    const float e0 = expf(acc0 - best);
    const float e1 = expf(acc1 - best);
    const float e2 = expf(acc2 - best);
    const float e3 = expf(acc3 - best);
    const float inv = 1.0f / (e0 + e1 + e2 + e3);

    const int m = mask[row];
    if (lane < 4) {
        const float rv = (m && lane == amax) ? 1.0f : 0.0f;
        __builtin_nontemporal_store(rv, out + OUT_R + (size_t)row * 4 + lane);
        if (m) {
            const float pv = (lane == 0 ? e0 : lane == 1 ? e1 : lane == 2 ? e2 : e3)
                             * inv * ws[SCAL_OFF];
            atomicAdd(&pcn[labels[row] * 4 + lane], pv);
        }
    }
}

// Pass 4: info-gain finalize over p_cn (1000 x 4) -> scalar
__global__ void __launch_bounds__(256) k_ig(const float* __restrict__ pcn,
                                            float* __restrict__ out) {
    __shared__ float red[256];
    __shared__ float pn_sh[4];
    const int t = threadIdx.x;

    float pn[4] = {0.f, 0.f, 0.f, 0.f};
    for (int c = t; c < C_SZ; c += 256) {
        pn[0] += pcn[c * 4 + 0];
        pn[1] += pcn[c * 4 + 1];
        pn[2] += pcn[c * 4 + 2];
        pn[3] += pcn[c * 4 + 3];
    }
#pragma unroll
    for (int n = 0; n < 4; ++n) {
        red[t] = pn[n];
        __syncthreads();
        for (int sft = 128; sft > 0; sft >>= 1) {
            if (t < sft) red[t] += red[t + sft];
            __syncthreads();
        }
        if (t == 0) pn_sh[n] = red[0];
        __syncthreads();
    }

    const float l0 = 2.0f * logf(pn_sh[0] + 1e-30f);
    const float l1 = 2.0f * logf(pn_sh[1] + 1e-30f);
    const float l2 = 2.0f * logf(pn_sh[2] + 1e-30f);
    const float l3 = 2.0f * logf(pn_sh[3] + 1e-30f);

    float kv = 0.f;
    for (int c = t; c < C_SZ; c += 256) {
        const float v0 = pcn[c * 4 + 0];
        const float v1 = pcn[c * 4 + 1];
        const float v2 = pcn[c * 4 + 2];
        const float v3 = pcn[c * 4 + 3];
        const float pc  = v0 + v1 + v2 + v3;
        const float lpc = logf(pc + 1e-30f);
        kv += v0 * (logf(v0 + 1e-30f) - lpc - l0);
        kv += v1 * (logf(v1 + 1e-30f) - lpc - l1);
        kv += v2 * (logf(v2 + 1e-30f) - lpc - l2);
        kv += v3 * (logf(v3 + 1e-30f) - lpc - l3);
    }
    red[t] = kv;
    __syncthreads();
    for (int sft = 128; sft > 0; sft >>= 1) {
        if (t < sft) red[t] += red[t + sft];
        __syncthreads();
    }
    if (t == 0) out[OUT_IG] = -red[0];
}

extern "C" void kernel_launch(void* const* d_in, const int* in_sizes, int n_in,
                              void* d_out, int out_size, void* d_ws, size_t ws_size,
                              hipStream_t stream) {
    const int*   ig_mask = (const int*)d_in[0];
    const float* h_net   = (const float*)d_in[1];
    const int*   labels  = (const int*)d_in[2];
    const float* gamma   = (const float*)d_in[3];
    const float* beta    = (const float*)d_in[4];
    const float* W       = (const float*)d_in[5];
    const float* b       = (const float*)d_in[6];

    float* out = (float*)d_out;
    float* ws  = (float*)d_ws;

    // p_cn must start at zero every launch (harness does not re-poison ws)
    (void)hipMemsetAsync(ws + PCN_OFF, 0, C_SZ * N_SZ * sizeof(float), stream);

    k_colsum<<<ROW_BLOCKS, 256, 0, stream>>>(h_net, ig_mask, ws);
    k_colfinal<<<H_SZ / 256, 256, 0, stream>>>(gamma, beta, ws);
    k_fused<<<B_SZ / 4, 256, 0, stream>>>(h_net, ig_mask, labels, W, b, ws, out,
                                          ws + PCN_OFF);
    k_ig<<<1, 256, 0, stream>>>(ws + PCN_OFF, out);
}

// Round 4
// 130.211 us; speedup vs baseline: 1.0280x; 1.0280x over previous
//
#include <hip/hip_runtime.h>
#include <cstddef>

#define B_SZ 32768
#define H_SZ 1024
#define N_SZ 4
#define C_SZ 1000
#define ROW_BLOCKS 512
#define ROWS_PER_BLOCK 64    // B_SZ / ROW_BLOCKS

// ---- workspace layout (in floats) ----
#define PART_SUM   0                                  // 512*1024
#define PART_SQ    (PART_SUM + ROW_BLOCKS*H_SZ)       // 512*1024
#define WSUM_PART  (PART_SQ  + ROW_BLOCKS*H_SZ)       // 512
#define A_OFF      (WSUM_PART + ROW_BLOCKS)           // 1024  (gamma * inv_std)
#define C_OFF      (A_OFF + H_SZ)                     // 1024  (beta - mean * a)
#define SCAL_OFF   (C_OFF + H_SZ)                     // 1 (inv_wsum)  (+7 pad)
#define PCN_OFF    (SCAL_OFF + 8)                     // 4000 (p_cn, zeroed in k_colsum)

// ---- output layout (floats) ----
#define OUT_IG  ((size_t)B_SZ * H_SZ)                 // 33554432
#define OUT_R   (OUT_IG + 1)                          // 33554433

// Pass 1: weighted column sums. Reads ALL rows (mask applied as a multiply) so
// the full 128 MiB of h_net lands in L3 for pass 3. Also zeroes p_cn (replaces
// the hipMemsetAsync node, which showed a 77us fence stall in R3).
__global__ void __launch_bounds__(256) k_colsum(const float* __restrict__ h,
                                                const int* __restrict__ mask,
                                                float* __restrict__ ws) {
    const int rb   = blockIdx.x;
    const int t    = threadIdx.x;          // 0..255
    const int row0 = rb * ROWS_PER_BLOCK;
    const int col  = t * 4;

    // zero p_cn: 512 blocks x 8 floats = 4096 >= 4000 (disjoint slices)
    if (t < 8) {
        const int idx = rb * 8 + t;
        if (idx < C_SZ * N_SZ) ws[PCN_OFF + idx] = 0.f;
    }

    float4 sA = make_float4(0.f, 0.f, 0.f, 0.f);
    float4 qA = make_float4(0.f, 0.f, 0.f, 0.f);
    float4 sB = make_float4(0.f, 0.f, 0.f, 0.f);
    float4 qB = make_float4(0.f, 0.f, 0.f, 0.f);
    int mc = 0;

    const float* p = h + (size_t)row0 * H_SZ + col;
    for (int r = 0; r < ROWS_PER_BLOCK; r += 2) {
        const int   ma = mask[row0 + r];
        const int   mb = mask[row0 + r + 1];
        const float wa = (float)ma;
        const float wb = (float)mb;
        const float4 xa = *(const float4*)(p);
        const float4 xb = *(const float4*)(p + H_SZ);
        mc += ma + mb;

        float tx;
        tx = wa * xa.x; sA.x += tx; qA.x = fmaf(tx, xa.x, qA.x);
        tx = wa * xa.y; sA.y += tx; qA.y = fmaf(tx, xa.y, qA.y);
        tx = wa * xa.z; sA.z += tx; qA.z = fmaf(tx, xa.z, qA.z);
        tx = wa * xa.w; sA.w += tx; qA.w = fmaf(tx, xa.w, qA.w);

        tx = wb * xb.x; sB.x += tx; qB.x = fmaf(tx, xb.x, qB.x);
        tx = wb * xb.y; sB.y += tx; qB.y = fmaf(tx, xb.y, qB.y);
        tx = wb * xb.z; sB.z += tx; qB.z = fmaf(tx, xb.z, qB.z);
        tx = wb * xb.w; sB.w += tx; qB.w = fmaf(tx, xb.w, qB.w);

        p += 2 * H_SZ;
    }
    sA.x += sB.x; sA.y += sB.y; sA.z += sB.z; sA.w += sB.w;
    qA.x += qB.x; qA.y += qB.y; qA.z += qB.z; qA.w += qB.w;

    *(float4*)(ws + PART_SUM + (size_t)rb * H_SZ + col) = sA;
    *(float4*)(ws + PART_SQ  + (size_t)rb * H_SZ + col) = qA;
    if (t == 0) ws[WSUM_PART + rb] = (float)mc;
}

// Pass 2: finalize mean/var -> a[h], c[h], inv_wsum
__global__ void __launch_bounds__(256) k_colfinal(const float* __restrict__ gamma,
                                                  const float* __restrict__ beta,
                                                  float* __restrict__ ws) {
    __shared__ float red[256];
    const int t = threadIdx.x;

    // every block redundantly reduces the 512 wsum partials
    red[t] = ws[WSUM_PART + t] + ws[WSUM_PART + 256 + t];
    __syncthreads();
    for (int sft = 128; sft > 0; sft >>= 1) {
        if (t < sft) red[t] += red[t + sft];
        __syncthreads();
    }
    const float wsum = red[0];

    const int h = blockIdx.x * 256 + t;
    float s = 0.f, q = 0.f;
    for (int rb = 0; rb < ROW_BLOCKS; ++rb) {
        s += ws[PART_SUM + (size_t)rb * H_SZ + h];
        q += ws[PART_SQ  + (size_t)rb * H_SZ + h];
    }
    const float inv_w = 1.0f / wsum;
    const float mean  = s * inv_w;
    float var = q * inv_w - mean * mean;
    if (var < 0.f) var = 0.f;
    const float istd = rsqrtf(var + 1e-5f);
    const float a = gamma[h] * istd;
    const float c = beta[h] - mean * a;
    ws[A_OFF + h] = a;
    ws[C_OFF + h] = c;
    if (h == 0) ws[SCAL_OFF] = inv_w;
}

// Pass 3: fused normalize + (BxH)@(Hx4) + softmax + argmax routing + p_cn atomics
// one wave (64 lanes) per row; block = 4 waves.
__global__ void __launch_bounds__(256) k_fused(const float* __restrict__ hin,
                                               const int* __restrict__ mask,
                                               const int* __restrict__ labels,
                                               const float* __restrict__ W,
                                               const float* __restrict__ bias,
                                               const float* __restrict__ ws,
                                               float* __restrict__ out,
                                               float* __restrict__ pcn) {
    const int wid  = threadIdx.x >> 6;
    const int lane = threadIdx.x & 63;
    const int row  = blockIdx.x * 4 + wid;

    const float* xr   = hin + (size_t)row * H_SZ;
    float*       outr = out + (size_t)row * H_SZ;

    float acc0 = 0.f, acc1 = 0.f, acc2 = 0.f, acc3 = 0.f;

#pragma unroll
    for (int ch = 0; ch < 4; ++ch) {
        const int h = ch * 256 + lane * 4;
        const float4 x = *(const float4*)(xr + h);
        const float4 a = *(const float4*)(ws + A_OFF + h);
        const float4 c = *(const float4*)(ws + C_OFF + h);
        float4 hn;
        hn.x = fmaf(x.x, a.x, c.x);
        hn.y = fmaf(x.y, a.y, c.y);
        hn.z = fmaf(x.z, a.z, c.z);
        hn.w = fmaf(x.w, a.w, c.w);
        *(float4*)(outr + h) = hn;

        const float4 w0 = *(const float4*)(W + (size_t)(h + 0) * 4);
        const float4 w1 = *(const float4*)(W + (size_t)(h + 1) * 4);
        const float4 w2 = *(const float4*)(W + (size_t)(h + 2) * 4);
        const float4 w3 = *(const float4*)(W + (size_t)(h + 3) * 4);
        acc0 = fmaf(hn.x, w0.x, acc0); acc1 = fmaf(hn.x, w0.y, acc1);
        acc2 = fmaf(hn.x, w0.z, acc2); acc3 = fmaf(hn.x, w0.w, acc3);
        acc0 = fmaf(hn.y, w1.x, acc0); acc1 = fmaf(hn.y, w1.y, acc1);
        acc2 = fmaf(hn.y, w1.z, acc2); acc3 = fmaf(hn.y, w1.w, acc3);
        acc0 = fmaf(hn.z, w2.x, acc0); acc1 = fmaf(hn.z, w2.y, acc1);
        acc2 = fmaf(hn.z, w2.z, acc2); acc3 = fmaf(hn.z, w2.w, acc3);
        acc0 = fmaf(hn.w, w3.x, acc0); acc1 = fmaf(hn.w, w3.y, acc1);
        acc2 = fmaf(hn.w, w3.z, acc2); acc3 = fmaf(hn.w, w3.w, acc3);
    }

    // wave reduce-all (64 lanes)
#pragma unroll
    for (int off = 1; off < 64; off <<= 1) {
        acc0 += __shfl_xor(acc0, off);
        acc1 += __shfl_xor(acc1, off);
        acc2 += __shfl_xor(acc2, off);
        acc3 += __shfl_xor(acc3, off);
    }
    acc0 += bias[0]; acc1 += bias[1]; acc2 += bias[2]; acc3 += bias[3];

    // first-occurrence argmax (matches jnp.argmax)
    int amax = 0; float best = acc0;
    if (acc1 > best) { best = acc1; amax = 1; }
    if (acc2 > best) { best = acc2; amax = 2; }
    if (acc3 > best) { best = acc3; amax = 3; }

    // softmax (TEMPERATURE = 1)
    const float e0 = expf(acc0 - best);
    const float e1 = expf(acc1 - best);
    const float e2 = expf(acc2 - best);
    const float e3 = expf(acc3 - best);
    const float inv = 1.0f / (e0 + e1 + e2 + e3);

    const int m = mask[row];
    if (lane < 4) {
        const float rv = (m && lane == amax) ? 1.0f : 0.0f;
        out[OUT_R + (size_t)row * 4 + lane] = rv;
        if (m) {
            const float pv = (lane == 0 ? e0 : lane == 1 ? e1 : lane == 2 ? e2 : e3)
                             * inv * ws[SCAL_OFF];
            atomicAdd(&pcn[labels[row] * 4 + lane], pv);
        }
    }
}

// Pass 4: info-gain finalize over p_cn (1000 x 4) -> scalar
__global__ void __launch_bounds__(256) k_ig(const float* __restrict__ pcn,
                                            float* __restrict__ out) {
    __shared__ float red[256];
    __shared__ float pn_sh[4];
    const int t = threadIdx.x;

    float pn[4] = {0.f, 0.f, 0.f, 0.f};
    for (int c = t; c < C_SZ; c += 256) {
        pn[0] += pcn[c * 4 + 0];
        pn[1] += pcn[c * 4 + 1];
        pn[2] += pcn[c * 4 + 2];
        pn[3] += pcn[c * 4 + 3];
    }
#pragma unroll
    for (int n = 0; n < 4; ++n) {
        red[t] = pn[n];
        __syncthreads();
        for (int sft = 128; sft > 0; sft >>= 1) {
            if (t < sft) red[t] += red[t + sft];
            __syncthreads();
        }
        if (t == 0) pn_sh[n] = red[0];
        __syncthreads();
    }

    const float l0 = 2.0f * logf(pn_sh[0] + 1e-30f);
    const float l1 = 2.0f * logf(pn_sh[1] + 1e-30f);
    const float l2 = 2.0f * logf(pn_sh[2] + 1e-30f);
    const float l3 = 2.0f * logf(pn_sh[3] + 1e-30f);

    float kv = 0.f;
    for (int c = t; c < C_SZ; c += 256) {
        const float v0 = pcn[c * 4 + 0];
        const float v1 = pcn[c * 4 + 1];
        const float v2 = pcn[c * 4 + 2];
        const float v3 = pcn[c * 4 + 3];
        const float pc  = v0 + v1 + v2 + v3;
        const float lpc = logf(pc + 1e-30f);
        kv += v0 * (logf(v0 + 1e-30f) - lpc - l0);
        kv += v1 * (logf(v1 + 1e-30f) - lpc - l1);
        kv += v2 * (logf(v2 + 1e-30f) - lpc - l2);
        kv += v3 * (logf(v3 + 1e-30f) - lpc - l3);
    }
    red[t] = kv;
    __syncthreads();
    for (int sft = 128; sft > 0; sft >>= 1) {
        if (t < sft) red[t] += red[t + sft];
        __syncthreads();
    }
    if (t == 0) out[OUT_IG] = -red[0];
}

extern "C" void kernel_launch(void* const* d_in, const int* in_sizes, int n_in,
                              void* d_out, int out_size, void* d_ws, size_t ws_size,
                              hipStream_t stream) {
    const int*   ig_mask = (const int*)d_in[0];
    const float* h_net   = (const float*)d_in[1];
    const int*   labels  = (const int*)d_in[2];
    const float* gamma   = (const float*)d_in[3];
    const float* beta    = (const float*)d_in[4];
    const float* W       = (const float*)d_in[5];
    const float* b       = (const float*)d_in[6];

    float* out = (float*)d_out;
    float* ws  = (float*)d_ws;

    k_colsum<<<ROW_BLOCKS, 256, 0, stream>>>(h_net, ig_mask, ws);
    k_colfinal<<<H_SZ / 256, 256, 0, stream>>>(gamma, beta, ws);
    k_fused<<<B_SZ / 4, 256, 0, stream>>>(h_net, ig_mask, labels, W, b, ws, out,
                                          ws + PCN_OFF);
    k_ig<<<1, 256, 0, stream>>>(ws + PCN_OFF, out);
}

// Round 5
// 97.374 us; speedup vs baseline: 1.3747x; 1.3372x over previous
//
#include <hip/hip_runtime.h>
#include <cstddef>

#define B_SZ 32768
#define H_SZ 1024
#define N_SZ 4
#define C_SZ 1000
#define ROW_BLOCKS 2048
#define ROWS_PER_BLOCK 16    // B_SZ / ROW_BLOCKS

// ---- workspace layout (in floats) ----
#define PART_SUM   0                                  // 2048*1024
#define PART_SQ    (PART_SUM + ROW_BLOCKS*H_SZ)       // 2048*1024
#define WSUM_PART  (PART_SQ  + ROW_BLOCKS*H_SZ)       // 2048
#define A_OFF      (WSUM_PART + ROW_BLOCKS)           // 1024  (gamma * inv_std)
#define C_OFF      (A_OFF + H_SZ)                     // 1024  (beta - mean * a)
#define SCAL_OFF   (C_OFF + H_SZ)                     // 1 (inv_wsum)  (+7 pad)
#define PCN_OFF    (SCAL_OFF + 8)                     // 4000 (p_cn, zeroed in k_colsum)

// ---- output layout (floats) ----
#define OUT_IG  ((size_t)B_SZ * H_SZ)                 // 33554432
#define OUT_R   (OUT_IG + 1)                          // 33554433

// Pass 1: weighted column sums over ALL rows (warms L3 for pass 3).
// 2048 blocks -> 8 waves/SIMD device-wide for latency hiding.
__global__ void __launch_bounds__(256) k_colsum(const float* __restrict__ h,
                                                const int* __restrict__ mask,
                                                float* __restrict__ ws) {
    const int rb   = blockIdx.x;
    const int t    = threadIdx.x;          // 0..255
    const int row0 = rb * ROWS_PER_BLOCK;
    const int col  = t * 4;

    // zero p_cn: blocks 0..499 each clear 8 floats (500*8 = 4000, disjoint)
    if (rb < 500 && t < 8) ws[PCN_OFF + rb * 8 + t] = 0.f;

    float4 sA = make_float4(0.f, 0.f, 0.f, 0.f);
    float4 qA = make_float4(0.f, 0.f, 0.f, 0.f);
    float4 sB = make_float4(0.f, 0.f, 0.f, 0.f);
    float4 qB = make_float4(0.f, 0.f, 0.f, 0.f);
    int mc = 0;

    const float* p = h + (size_t)row0 * H_SZ + col;
#pragma unroll
    for (int r = 0; r < ROWS_PER_BLOCK; r += 2) {
        const int   ma = mask[row0 + r];
        const int   mb = mask[row0 + r + 1];
        const float wa = (float)ma;
        const float wb = (float)mb;
        const float4 xa = *(const float4*)(p);
        const float4 xb = *(const float4*)(p + H_SZ);
        mc += ma + mb;

        float tx;
        tx = wa * xa.x; sA.x += tx; qA.x = fmaf(tx, xa.x, qA.x);
        tx = wa * xa.y; sA.y += tx; qA.y = fmaf(tx, xa.y, qA.y);
        tx = wa * xa.z; sA.z += tx; qA.z = fmaf(tx, xa.z, qA.z);
        tx = wa * xa.w; sA.w += tx; qA.w = fmaf(tx, xa.w, qA.w);

        tx = wb * xb.x; sB.x += tx; qB.x = fmaf(tx, xb.x, qB.x);
        tx = wb * xb.y; sB.y += tx; qB.y = fmaf(tx, xb.y, qB.y);
        tx = wb * xb.z; sB.z += tx; qB.z = fmaf(tx, xb.z, qB.z);
        tx = wb * xb.w; sB.w += tx; qB.w = fmaf(tx, xb.w, qB.w);

        p += 2 * H_SZ;
    }
    sA.x += sB.x; sA.y += sB.y; sA.z += sB.z; sA.w += sB.w;
    qA.x += qB.x; qA.y += qB.y; qA.z += qB.z; qA.w += qB.w;

    *(float4*)(ws + PART_SUM + (size_t)rb * H_SZ + col) = sA;
    *(float4*)(ws + PART_SQ  + (size_t)rb * H_SZ + col) = qA;
    if (t == 0) ws[WSUM_PART + rb] = (float)mc;
}

// Pass 2: finalize mean/var -> a[h], c[h], inv_wsum.
// 64 blocks; block handles 16 columns, 16 strips of 128 partials each.
__global__ void __launch_bounds__(256) k_colfinal(const float* __restrict__ gamma,
                                                  const float* __restrict__ beta,
                                                  float* __restrict__ ws) {
    __shared__ float red[256];
    __shared__ float sh_s[16][17];
    __shared__ float sh_q[16][17];
    const int t = threadIdx.x;

    // wsum: every block reduces the 2048 mask-count partials
    float w = 0.f;
#pragma unroll
    for (int i = 0; i < ROW_BLOCKS / 256; ++i) w += ws[WSUM_PART + i * 256 + t];
    red[t] = w;
    __syncthreads();
    for (int sft = 128; sft > 0; sft >>= 1) {
        if (t < sft) red[t] += red[t + sft];
        __syncthreads();
    }
    const float wsum = red[0];

    const int c16   = t & 15;
    const int strip = t >> 4;                  // 0..15
    const int col   = blockIdx.x * 16 + c16;

    float s = 0.f, q = 0.f;
    const int rb0 = strip * (ROW_BLOCKS / 16);
    for (int k = 0; k < ROW_BLOCKS / 16; ++k) {
        s += ws[PART_SUM + (size_t)(rb0 + k) * H_SZ + col];
        q += ws[PART_SQ  + (size_t)(rb0 + k) * H_SZ + col];
    }
    sh_s[strip][c16] = s;
    sh_q[strip][c16] = q;
    __syncthreads();

    if (t < 16) {
        float S = 0.f, Q = 0.f;
#pragma unroll
        for (int k = 0; k < 16; ++k) { S += sh_s[k][t]; Q += sh_q[k][t]; }
        const int hcol = blockIdx.x * 16 + t;
        const float inv_w = 1.0f / wsum;
        const float mean  = S * inv_w;
        float var = Q * inv_w - mean * mean;
        if (var < 0.f) var = 0.f;
        const float istd = rsqrtf(var + 1e-5f);
        const float a = gamma[hcol] * istd;
        const float c = beta[hcol] - mean * a;
        ws[A_OFF + hcol] = a;
        ws[C_OFF + hcol] = c;
        if (blockIdx.x == 0 && t == 0) ws[SCAL_OFF] = inv_w;
    }
}

// Pass 3: fused normalize + (BxH)@(Hx4) + softmax + argmax routing + p_cn atomics.
// Persistent-ish: 2048 blocks, each wave owns 4 consecutive rows, fully
// unrolled with next-row x prefetch; a/c cached in registers.
__global__ void __launch_bounds__(256, 4) k_fused(const float* __restrict__ hin,
                                                  const int* __restrict__ mask,
                                                  const int* __restrict__ labels,
                                                  const float* __restrict__ W,
                                                  const float* __restrict__ bias,
                                                  const float* __restrict__ ws,
                                                  float* __restrict__ out,
                                                  float* __restrict__ pcn) {
    const int wid  = threadIdx.x >> 6;
    const int lane = threadIdx.x & 63;
    const int gw   = blockIdx.x * 4 + wid;    // 0..8191
    const int row0 = gw * 4;

    // cache normalize coefficients for this lane's 16 columns
    float4 a4[4], c4[4];
#pragma unroll
    for (int ch = 0; ch < 4; ++ch) {
        const int h = ch * 256 + lane * 4;
        a4[ch] = *(const float4*)(ws + A_OFF + h);
        c4[ch] = *(const float4*)(ws + C_OFF + h);
    }
    const float inv_w = ws[SCAL_OFF];
    const float b0 = bias[0], b1 = bias[1], b2 = bias[2], b3 = bias[3];

    float4 xA[4];
#pragma unroll
    for (int ch = 0; ch < 4; ++ch)
        xA[ch] = *(const float4*)(hin + (size_t)row0 * H_SZ + ch * 256 + lane * 4);

#pragma unroll
    for (int r = 0; r < 4; ++r) {
        const int row = row0 + r;
        float4 xB[4];
        if (r < 3) {
#pragma unroll
            for (int ch = 0; ch < 4; ++ch)
                xB[ch] = *(const float4*)(hin + (size_t)(row + 1) * H_SZ + ch * 256 + lane * 4);
        }

        float acc0 = 0.f, acc1 = 0.f, acc2 = 0.f, acc3 = 0.f;
        float* outr = out + (size_t)row * H_SZ;

#pragma unroll
        for (int ch = 0; ch < 4; ++ch) {
            const int h = ch * 256 + lane * 4;
            float4 hn;
            hn.x = fmaf(xA[ch].x, a4[ch].x, c4[ch].x);
            hn.y = fmaf(xA[ch].y, a4[ch].y, c4[ch].y);
            hn.z = fmaf(xA[ch].z, a4[ch].z, c4[ch].z);
            hn.w = fmaf(xA[ch].w, a4[ch].w, c4[ch].w);
            *(float4*)(outr + h) = hn;

            const float4 w0 = *(const float4*)(W + (size_t)(h + 0) * 4);
            const float4 w1 = *(const float4*)(W + (size_t)(h + 1) * 4);
            const float4 w2 = *(const float4*)(W + (size_t)(h + 2) * 4);
            const float4 w3 = *(const float4*)(W + (size_t)(h + 3) * 4);
            acc0 = fmaf(hn.x, w0.x, acc0); acc1 = fmaf(hn.x, w0.y, acc1);
            acc2 = fmaf(hn.x, w0.z, acc2); acc3 = fmaf(hn.x, w0.w, acc3);
            acc0 = fmaf(hn.y, w1.x, acc0); acc1 = fmaf(hn.y, w1.y, acc1);
            acc2 = fmaf(hn.y, w1.z, acc2); acc3 = fmaf(hn.y, w1.w, acc3);
            acc0 = fmaf(hn.z, w2.x, acc0); acc1 = fmaf(hn.z, w2.y, acc1);
            acc2 = fmaf(hn.z, w2.z, acc2); acc3 = fmaf(hn.z, w2.w, acc3);
            acc0 = fmaf(hn.w, w3.x, acc0); acc1 = fmaf(hn.w, w3.y, acc1);
            acc2 = fmaf(hn.w, w3.z, acc2); acc3 = fmaf(hn.w, w3.w, acc3);
        }

        // wave reduce-all (64 lanes)
#pragma unroll
        for (int off = 1; off < 64; off <<= 1) {
            acc0 += __shfl_xor(acc0, off);
            acc1 += __shfl_xor(acc1, off);
            acc2 += __shfl_xor(acc2, off);
            acc3 += __shfl_xor(acc3, off);
        }
        acc0 += b0; acc1 += b1; acc2 += b2; acc3 += b3;

        // first-occurrence argmax (matches jnp.argmax)
        int amax = 0; float best = acc0;
        if (acc1 > best) { best = acc1; amax = 1; }
        if (acc2 > best) { best = acc2; amax = 2; }
        if (acc3 > best) { best = acc3; amax = 3; }

        // softmax (TEMPERATURE = 1)
        const float e0 = expf(acc0 - best);
        const float e1 = expf(acc1 - best);
        const float e2 = expf(acc2 - best);
        const float e3 = expf(acc3 - best);
        const float inv = 1.0f / (e0 + e1 + e2 + e3);

        const int m = mask[row];
        if (lane < 4) {
            const float rv = (m && lane == amax) ? 1.0f : 0.0f;
            out[OUT_R + (size_t)row * 4 + lane] = rv;
            if (m) {
                const float pv = (lane == 0 ? e0 : lane == 1 ? e1 : lane == 2 ? e2 : e3)
                                 * inv * inv_w;
                atomicAdd(&pcn[labels[row] * 4 + lane], pv);
            }
        }

        if (r < 3) {
#pragma unroll
            for (int ch = 0; ch < 4; ++ch) xA[ch] = xB[ch];
        }
    }
}

// Pass 4: info-gain finalize over p_cn (1000 x 4) -> scalar
__global__ void __launch_bounds__(256) k_ig(const float* __restrict__ pcn,
                                            float* __restrict__ out) {
    __shared__ float red[256];
    __shared__ float pn_sh[4];
    const int t = threadIdx.x;

    float pn[4] = {0.f, 0.f, 0.f, 0.f};
    for (int c = t; c < C_SZ; c += 256) {
        pn[0] += pcn[c * 4 + 0];
        pn[1] += pcn[c * 4 + 1];
        pn[2] += pcn[c * 4 + 2];
        pn[3] += pcn[c * 4 + 3];
    }
#pragma unroll
    for (int n = 0; n < 4; ++n) {
        red[t] = pn[n];
        __syncthreads();
        for (int sft = 128; sft > 0; sft >>= 1) {
            if (t < sft) red[t] += red[t + sft];
            __syncthreads();
        }
        if (t == 0) pn_sh[n] = red[0];
        __syncthreads();
    }

    const float l0 = 2.0f * logf(pn_sh[0] + 1e-30f);
    const float l1 = 2.0f * logf(pn_sh[1] + 1e-30f);
    const float l2 = 2.0f * logf(pn_sh[2] + 1e-30f);
    const float l3 = 2.0f * logf(pn_sh[3] + 1e-30f);

    float kv = 0.f;
    for (int c = t; c < C_SZ; c += 256) {
        const float v0 = pcn[c * 4 + 0];
        const float v1 = pcn[c * 4 + 1];
        const float v2 = pcn[c * 4 + 2];
        const float v3 = pcn[c * 4 + 3];
        const float pc  = v0 + v1 + v2 + v3;
        const float lpc = logf(pc + 1e-30f);
        kv += v0 * (logf(v0 + 1e-30f) - lpc - l0);
        kv += v1 * (logf(v1 + 1e-30f) - lpc - l1);
        kv += v2 * (logf(v2 + 1e-30f) - lpc - l2);
        kv += v3 * (logf(v3 + 1e-30f) - lpc - l3);
    }
    red[t] = kv;
    __syncthreads();
    for (int sft = 128; sft > 0; sft >>= 1) {
        if (t < sft) red[t] += red[t + sft];
        __syncthreads();
    }
    if (t == 0) out[OUT_IG] = -red[0];
}

extern "C" void kernel_launch(void* const* d_in, const int* in_sizes, int n_in,
                              void* d_out, int out_size, void* d_ws, size_t ws_size,
                              hipStream_t stream) {
    const int*   ig_mask = (const int*)d_in[0];
    const float* h_net   = (const float*)d_in[1];
    const int*   labels  = (const int*)d_in[2];
    const float* gamma   = (const float*)d_in[3];
    const float* beta    = (const float*)d_in[4];
    const float* W       = (const float*)d_in[5];
    const float* b       = (const float*)d_in[6];

    float* out = (float*)d_out;
    float* ws  = (float*)d_ws;

    k_colsum<<<ROW_BLOCKS, 256, 0, stream>>>(h_net, ig_mask, ws);
    k_colfinal<<<H_SZ / 16, 256, 0, stream>>>(gamma, beta, ws);
    k_fused<<<B_SZ / 16, 256, 0, stream>>>(h_net, ig_mask, labels, W, b, ws, out,
                                           ws + PCN_OFF);
    k_ig<<<1, 256, 0, stream>>>(ws + PCN_OFF, out);
}